// Round 1
// baseline (507.750 us; speedup 1.0000x reference)
//
#include <hip/hip_runtime.h>
#include <hip/hip_bf16.h>

#define N_NODES 10000
#define N_PAIRS 200000
#define NFEAT 384
#define FH 128
#define SPH 15

typedef __bf16 bf16x8 __attribute__((ext_vector_type(8)));
typedef float f32x4 __attribute__((ext_vector_type(4)));

// float32 -> bf16 conversion, 4 elements/thread
__global__ void cvt4_kernel(const float* __restrict__ in, unsigned short* __restrict__ out, int n4) {
    int t = blockIdx.x * blockDim.x + threadIdx.x;
    if (t >= n4) return;
    float4 v = ((const float4*)in)[t];
    __hip_bfloat16 b0 = __float2bfloat16(v.x);
    __hip_bfloat16 b1 = __float2bfloat16(v.y);
    __hip_bfloat16 b2 = __float2bfloat16(v.z);
    __hip_bfloat16 b3 = __float2bfloat16(v.w);
    ushort4 o;
    o.x = __builtin_bit_cast(unsigned short, b0);
    o.y = __builtin_bit_cast(unsigned short, b1);
    o.z = __builtin_bit_cast(unsigned short, b2);
    o.w = __builtin_bit_cast(unsigned short, b3);
    ((ushort4*)out)[t] = o;
}

// q[n, h*128+g] = sum_f x[n, h*128+f] * Wq[h, g, f]   (and same for k)
// One block = 16 nodes x 1 head. 4 waves x 4 tasks: task = (g-tile 0..7) x (q|k).
// MFMA 16x16x32 bf16: A[m=lane&15][k=quad*8+j], B[k=quad*8+j][n=lane&15],
// D: col=lane&15, row=quad*4+reg  (verified gfx950 mapping).
__global__ void qk_gemm_kernel(const unsigned short* __restrict__ xb,
                               const unsigned short* __restrict__ Wqb,
                               const unsigned short* __restrict__ Wkb,
                               float* __restrict__ q, float* __restrict__ k) {
    const int head = blockIdx.y;
    const int node0 = blockIdx.x * 16;
    const int wave = threadIdx.x >> 6;
    const int lane = threadIdx.x & 63;
    const int mrow = lane & 15;   // A row (node) / B col (g)
    const int quad = lane >> 4;   // 0..3
    const unsigned short* xrow = xb + (size_t)(node0 + mrow) * NFEAT + head * FH + quad * 8;
    for (int task = wave; task < 16; task += 4) {
        const int mat = task & 1;
        const int g0 = (task >> 1) * 16;
        const unsigned short* Wrow =
            (mat ? Wkb : Wqb) + (size_t)head * FH * FH + (size_t)(g0 + mrow) * FH + quad * 8;
        f32x4 acc = {0.f, 0.f, 0.f, 0.f};
#pragma unroll
        for (int k0 = 0; k0 < FH; k0 += 32) {
            bf16x8 a = *(const bf16x8*)(xrow + k0);
            bf16x8 b = *(const bf16x8*)(Wrow + k0);
            acc = __builtin_amdgcn_mfma_f32_16x16x32_bf16(a, b, acc, 0, 0, 0);
        }
        float* dst = mat ? k : q;
        const int g = g0 + (lane & 15);
#pragma unroll
        for (int r = 0; r < 4; ++r) {
            const int node = node0 + quad * 4 + r;
            dst[(size_t)node * NFEAT + head * FH + g] = acc[r];
        }
    }
}

// One wave per pair. Lane l owns features {2l, 2l+1} of each head (float2).
// alpha[h] = (sum_f q[i,h,f]*w[e,h,f]*k[j,h,f]) / sqrt(128) * (phi_r[e]+phi_chi[e])
// then lanes 0..14 scatter alpha_rep[c]*sph[e,c] into out[i,c].
__global__ void pair_kernel(const float* __restrict__ q, const float* __restrict__ kk,
                            const float* __restrict__ w_ij, const float* __restrict__ sph,
                            const int* __restrict__ idx_i, const int* __restrict__ idx_j,
                            const float* __restrict__ phi_r, const float* __restrict__ phi_chi,
                            float* __restrict__ out) {
    const int lane = threadIdx.x & 63;
    const int wid = blockIdx.x * (blockDim.x >> 6) + (threadIdx.x >> 6);
    const int nw = gridDim.x * (blockDim.x >> 6);
    for (int e = wid; e < N_PAIRS; e += nw) {
        const int i = idx_i[e];
        const int j = idx_j[e];
        const float* qr = q + (size_t)i * NFEAT;
        const float* kr = kk + (size_t)j * NFEAT;
        const float* wr = w_ij + (size_t)e * NFEAT;
        float dot[3];
#pragma unroll
        for (int h = 0; h < 3; ++h) {
            const int f = h * FH + 2 * lane;
            float2 q2 = *(const float2*)(qr + f);
            float2 w2 = *(const float2*)(wr + f);
            float2 k2 = *(const float2*)(kr + f);
            float p = q2.x * w2.x * k2.x + q2.y * w2.y * k2.y;
#pragma unroll
            for (int off = 32; off; off >>= 1) p += __shfl_xor(p, off, 64);
            dot[h] = p;
        }
        const float scale = (phi_r[e] + phi_chi[e]) * 0.088388347648318447f;  // 1/sqrt(128)
        if (lane < SPH) {
            const int h = (lane < 3) ? 0 : (lane < 8 ? 1 : 2);
            const float val = dot[h] * scale * sph[(size_t)e * SPH + lane];
            unsafeAtomicAdd(&out[(size_t)i * SPH + lane], val);
        }
    }
}

extern "C" void kernel_launch(void* const* d_in, const int* in_sizes, int n_in,
                              void* d_out, int out_size, void* d_ws, size_t ws_size,
                              hipStream_t stream) {
    // inputs: 0 chi (unused), 1 sph_ij, 2 x, 3 w_ij, 4 idx_i, 5 phi_r_cut,
    //         6 phi_chi_cut, 7 idx_j, 8 Wq, 9 Wk
    const float* sph     = (const float*)d_in[1];
    const float* x       = (const float*)d_in[2];
    const float* w_ij    = (const float*)d_in[3];
    const int*   idx_i   = (const int*)d_in[4];
    const float* phi_r   = (const float*)d_in[5];
    const float* phi_chi = (const float*)d_in[6];
    const int*   idx_j   = (const int*)d_in[7];
    const float* Wq      = (const float*)d_in[8];
    const float* Wk      = (const float*)d_in[9];
    float* out = (float*)d_out;

    // workspace layout (38.6 MB total)
    char* ws = (char*)d_ws;
    float* qws = (float*)ws;                                   // 10000*384*4 = 15,360,000
    float* kws = (float*)(ws + 15360000);                      // 15,360,000
    unsigned short* xb  = (unsigned short*)(ws + 30720000);    // 7,680,000
    unsigned short* Wqb = (unsigned short*)(ws + 38400000);    // 98,304
    unsigned short* Wkb = (unsigned short*)(ws + 38498304);    // 98,304

    hipMemsetAsync(d_out, 0, (size_t)out_size * sizeof(float), stream);

    cvt4_kernel<<<3750, 256, 0, stream>>>(x, xb, N_NODES * NFEAT / 4);      // 960000
    cvt4_kernel<<<48, 256, 0, stream>>>(Wq, Wqb, 3 * FH * FH / 4);          // 12288
    cvt4_kernel<<<48, 256, 0, stream>>>(Wk, Wkb, 3 * FH * FH / 4);          // 12288

    qk_gemm_kernel<<<dim3(N_NODES / 16, 3), 256, 0, stream>>>(xb, Wqb, Wkb, qws, kws);

    pair_kernel<<<2048, 256, 0, stream>>>(qws, kws, w_ij, sph, idx_i, idx_j,
                                          phi_r, phi_chi, out);
}

// Round 2
// 502.790 us; speedup vs baseline: 1.0099x; 1.0099x over previous
//
#include <hip/hip_runtime.h>
#include <hip/hip_bf16.h>

#define N_NODES 10000
#define N_PAIRS 200000
#define NFEAT 384
#define FH 128
#define SPH 15

typedef __bf16 bf16x8 __attribute__((ext_vector_type(8)));
typedef float f32x4 __attribute__((ext_vector_type(4)));

// q[n, h*128+g] = sum_f x[n, h*128+f] * Wq[h, g, f]   (and same for k)
// One block = 16 nodes x 1 head; f32 inputs converted to bf16 in-registers.
// 4 waves x 4 tasks: task = (g-tile 0..7) x (q|k).
// MFMA 16x16x32 bf16: A[m=lane&15][k=quad*8+j], B[k=quad*8+j][n=lane&15],
// D: col=lane&15, row=quad*4+reg  (verified gfx950 mapping).
__device__ inline bf16x8 cvt8(const float* __restrict__ p) {
    float4 lo = *(const float4*)p;
    float4 hi = *(const float4*)(p + 4);
    bf16x8 r;
    r[0] = (__bf16)lo.x; r[1] = (__bf16)lo.y; r[2] = (__bf16)lo.z; r[3] = (__bf16)lo.w;
    r[4] = (__bf16)hi.x; r[5] = (__bf16)hi.y; r[6] = (__bf16)hi.z; r[7] = (__bf16)hi.w;
    return r;
}

__global__ void qk_gemm_kernel(const float* __restrict__ x,
                               const float* __restrict__ Wq,
                               const float* __restrict__ Wk,
                               float* __restrict__ q, float* __restrict__ k) {
    const int head = blockIdx.y;
    const int node0 = blockIdx.x * 16;
    const int wave = threadIdx.x >> 6;
    const int lane = threadIdx.x & 63;
    const int mrow = lane & 15;   // A row (node) / B row (g)
    const int quad = lane >> 4;   // 0..3
    const float* xrow = x + (size_t)(node0 + mrow) * NFEAT + head * FH + quad * 8;
    // A fragment (16 nodes x 128 k) converted once, reused for all 16 tasks
    bf16x8 afrag[4];
#pragma unroll
    for (int t = 0; t < 4; ++t) afrag[t] = cvt8(xrow + t * 32);

    for (int task = wave; task < 16; task += 4) {
        const int mat = task & 1;
        const int g0 = (task >> 1) * 16;
        const float* Wrow =
            (mat ? Wk : Wq) + (size_t)head * FH * FH + (size_t)(g0 + mrow) * FH + quad * 8;
        f32x4 acc = {0.f, 0.f, 0.f, 0.f};
#pragma unroll
        for (int t = 0; t < 4; ++t) {
            bf16x8 b = cvt8(Wrow + t * 32);
            acc = __builtin_amdgcn_mfma_f32_16x16x32_bf16(afrag[t], b, acc, 0, 0, 0);
        }
        float* dst = mat ? k : q;
        const int g = g0 + mrow;
#pragma unroll
        for (int r = 0; r < 4; ++r) {
            const int node = node0 + quad * 4 + r;
            dst[(size_t)node * NFEAT + head * FH + g] = acc[r];
        }
    }
}

// 4 pairs per wave, 16 lanes per pair. Lane `sub` owns 8 feats/head (float4 x2).
// alpha[h] = (sum_f q[i,h,f]*w[e,h,f]*k[j,h,f]) / sqrt(128) * (phi_r[e]+phi_chi[e])
// then subs 0..14 of each group scatter alpha_rep[c]*sph[e,c] into out[i,c].
__global__ void pair_kernel(const float* __restrict__ q, const float* __restrict__ kk,
                            const float* __restrict__ w_ij, const float* __restrict__ sph,
                            const int* __restrict__ idx_i, const int* __restrict__ idx_j,
                            const float* __restrict__ phi_r, const float* __restrict__ phi_chi,
                            float* __restrict__ out) {
    const int lane = threadIdx.x & 63;
    const int sub = lane & 15;   // lane within pair-group
    const int grp = lane >> 4;   // which of 4 pairs in this wave
    const int wid = blockIdx.x * (blockDim.x >> 6) + (threadIdx.x >> 6);
    const int nw = gridDim.x * (blockDim.x >> 6);
    for (int base = wid * 4; base < N_PAIRS; base += nw * 4) {
        const int e = base + grp;
        if (e < N_PAIRS) {
            const int i = idx_i[e];
            const int j = idx_j[e];
            const float* qr = q + (size_t)i * NFEAT;
            const float* kr = kk + (size_t)j * NFEAT;
            const float* wr = w_ij + (size_t)e * NFEAT;
            float dot[3];
#pragma unroll
            for (int h = 0; h < 3; ++h) {
                const int f = h * FH + sub * 8;
                float4 qa = *(const float4*)(qr + f);
                float4 qb = *(const float4*)(qr + f + 4);
                float4 wa = *(const float4*)(wr + f);
                float4 wb = *(const float4*)(wr + f + 4);
                float4 ka = *(const float4*)(kr + f);
                float4 kb = *(const float4*)(kr + f + 4);
                float p = qa.x * wa.x * ka.x;
                p = fmaf(qa.y * wa.y, ka.y, p);
                p = fmaf(qa.z * wa.z, ka.z, p);
                p = fmaf(qa.w * wa.w, ka.w, p);
                p = fmaf(qb.x * wb.x, kb.x, p);
                p = fmaf(qb.y * wb.y, kb.y, p);
                p = fmaf(qb.z * wb.z, kb.z, p);
                p = fmaf(qb.w * wb.w, kb.w, p);
                // reduce across the 16-lane group
#pragma unroll
                for (int off = 8; off; off >>= 1) p += __shfl_xor(p, off, 16);
                dot[h] = p;
            }
            const float scale = (phi_r[e] + phi_chi[e]) * 0.088388347648318447f;  // 1/sqrt(128)
            if (sub < SPH) {
                const int h = (sub < 3) ? 0 : (sub < 8 ? 1 : 2);
                const float val = dot[h] * scale * sph[(size_t)e * SPH + sub];
                unsafeAtomicAdd(&out[(size_t)i * SPH + sub], val);
            }
        }
    }
}

extern "C" void kernel_launch(void* const* d_in, const int* in_sizes, int n_in,
                              void* d_out, int out_size, void* d_ws, size_t ws_size,
                              hipStream_t stream) {
    // inputs: 0 chi (unused), 1 sph_ij, 2 x, 3 w_ij, 4 idx_i, 5 phi_r_cut,
    //         6 phi_chi_cut, 7 idx_j, 8 Wq, 9 Wk
    const float* sph     = (const float*)d_in[1];
    const float* x       = (const float*)d_in[2];
    const float* w_ij    = (const float*)d_in[3];
    const int*   idx_i   = (const int*)d_in[4];
    const float* phi_r   = (const float*)d_in[5];
    const float* phi_chi = (const float*)d_in[6];
    const int*   idx_j   = (const int*)d_in[7];
    const float* Wq      = (const float*)d_in[8];
    const float* Wk      = (const float*)d_in[9];
    float* out = (float*)d_out;

    // workspace layout: q (15.36 MB) + k (15.36 MB)
    char* ws = (char*)d_ws;
    float* qws = (float*)ws;
    float* kws = (float*)(ws + 15360000);

    hipMemsetAsync(d_out, 0, (size_t)out_size * sizeof(float), stream);

    qk_gemm_kernel<<<dim3(N_NODES / 16, 3), 256, 0, stream>>>(x, Wq, Wk, qws, kws);

    pair_kernel<<<2048, 256, 0, stream>>>(qws, kws, w_ij, sph, idx_i, idx_j,
                                          phi_r, phi_chi, out);
}